// Round 19
// baseline (202.333 us; speedup 1.0000x reference)
//
#include <hip/hip_runtime.h>
#include <math.h>

#define NB 4
#define NP 8192
#define KK 16
#define QPB 64
#define NPTS (NB * NP)

// ---- geometry (round 19: branchless append + register butterfly merge) ----
#define TSAMP 2048            // tau sample = candidates [0,2048)
#define TTCH 256              // tau subchunk per wave (2048/8)
#define BCH 1024              // filter chunk size
#define NBCH 8                // 8 chunks cover [0,8192)
#define CAP 30                // per-(query,chunk) capacity (R13-proven geometry)
#define SROW 34               // u16 per (chunk,query) LDS row (odd dwords)
#define SCH (64 * SROW + 2)   // LDS chunk stride in u16 (=2178)
#define PADKEY 0xFFFFFFFFFFFFull   // 48-bit all-ones
#define TAU_MARGIN 2.5e-4f    // >= 2x the |diff_d - ref_d| bound (~3.5e-5)
// Dynamic LDS (36,128 B):
//   [0,34848)   union{ samp float4[1536] (24,576B) -> s_t f32[8][64][17]
//               (34,816B) -> s_idx u16 8x2178 (34,848B) }  (barriered phases)
//   [34848,35872) s_cnt u16[8][64];  [35872,36128) s_tau f32[64].
//
// Correctness chain (fail-safe, independent of tau's value):
//  S = {j: diff_d(j) <= tau + MARGIN}, tau = 16th-smallest diff_d over the
//  2048-sample; |diff_d - ref_d| <= ~3.5e-5 << MARGIN => exact ref top-16
//  inside S whenever |S| >= 16. Phase 2 re-ranks S with EXACT ref-rounded
//  distance; 48-bit key (ord(d)<<16)|j gives the total order (d asc, j asc).
//  Per-chunk top-16-by-key then 8-way merge == global top-16 (any global
//  top-16 element is in its chunk's top-16). Butterfly halver+bitonic merge
//  is deterministic => all lanes get the identical sorted array == the
//  proven tournament's output (absmax 0.0, R12-R18). Chunk cnt > CAP or
//  total < 16 => in-kernel exact full-scan.
//  Branchless append: every candidate writes Srow[1+min(cnt,CAP)] then cnt
//  advances only on hit; the last writer of every position < cnt is a hit,
//  so the final list is exactly the survivor indices in ascending order.

// comparator macros (exact: min/max introduce no rounding)
#define CSWAP_DESC(a, b) { float _lo = fminf(a, b); float _hi = fmaxf(a, b); a = _hi; b = _lo; }
#define CSWAP_ASC(a, b)  { float _lo = fminf(a, b); float _hi = fmaxf(a, b); a = _lo; b = _hi; }
#define CSWAP_U64(a, b)  { unsigned long long _lo = (a < b) ? a : b; \
                           unsigned long long _hi = (a < b) ? b : a; a = _lo; b = _hi; }

__device__ __forceinline__ float ref_sq(float x, float y, float z) {
  return __fadd_rn(__fadd_rn(__fmul_rn(x, x), __fmul_rn(y, y)), __fmul_rn(z, z));
}

// reference-rounded d2 = (sqq + sqc) - 2*dot (the exact selection metric)
__device__ __forceinline__ float ref_d2(float qx, float qy, float qz, float sqq,
                                        float cx, float cy, float cz) {
  float sqc = ref_sq(cx, cy, cz);
  float dot = __fadd_rn(__fadd_rn(__fmul_rn(qx, cx), __fmul_rn(qy, cy)),
                        __fmul_rn(qz, cz));
  float s = __fadd_rn(sqq, sqc);
  return __fmaf_rn(-2.0f, dot, s);
}

// diff-form distance (6 VALU, near-exact): used for tau + filter only
__device__ __forceinline__ float diff_d2(float qx, float qy, float qz,
                                         float cx, float cy, float cz) {
  float dx = cx - qx, dy = cy - qy, dz = cz - qz;
  return __fmaf_rn(dz, dz, __fmaf_rn(dy, dy, dx * dx));
}

// order-preserving float->u32 (total order == float compare for non-NaN)
__device__ __forceinline__ unsigned int ord_f32(float d) {
  unsigned int b = __float_as_uint(d);
  return b ^ ((b >> 31) ? 0xFFFFFFFFu : 0x80000000u);
}

// ---- eigen-ratio tail (R11-R18-proven: absmax 0.0 measured) ----
__device__ __forceinline__ double eigen_ratio_tail(
    float cxx, float cyy, float czz, float cxy, float cxz, float cyz,
    float k1) {
  double a   = (double)__fmul_rn(cxx, k1), b = (double)__fmul_rn(cyy, k1);
  double c2  = (double)__fmul_rn(czz, k1);
  double dxy = (double)__fmul_rn(cxy, k1), exz = (double)__fmul_rn(cxz, k1);
  double fyz = (double)__fmul_rn(cyz, k1);
  double qm = (a + b + c2) / 3.0;
  double p1 = dxy * dxy + exz * exz + fyz * fyz;
  double aa = a - qm, bb = b - qm, cc = c2 - qm;
  double p2 = aa * aa + bb * bb + cc * cc + 2.0 * p1;
  if (p2 <= 0.0) return 1.0;
  double p  = sqrt(p2 / 6.0);
  double ip = 1.0 / p;
  double b00 = aa * ip, b11 = bb * ip, b22 = cc * ip;
  double b01 = dxy * ip, b02 = exz * ip, b12 = fyz * ip;
  double detB = b00 * (b11 * b22 - b12 * b12)
              - b01 * (b01 * b22 - b12 * b02)
              + b02 * (b01 * b12 - b11 * b02);
  double r = 0.5 * detB;
  r = fmin(1.0, fmax(-1.0, r));
  const double dcl = 2.0 * r;
  float phif = acosf((float)r) * (1.0f / 3.0f);
  double y0 = 2.0 * (double)cosf(phif);
  double y2 = 2.0 * (double)cosf(phif + 2.0943951f);
#pragma unroll
  for (int it = 0; it < 3; ++it) {
    double g0 = 3.0 * (y0 * y0 - 1.0);
    if (fabs(g0) > 1e-4) y0 -= (y0 * y0 * y0 - 3.0 * y0 - dcl) / g0;
    double g2 = 3.0 * (y2 * y2 - 1.0);
    if (fabs(g2) > 1e-4) y2 -= (y2 * y2 * y2 - 3.0 * y2 - dcl) / g2;
  }
  double e0 = qm + p * y0;
  double e2v = qm + p * y2;
  double e1 = 3.0 * qm - e0 - e2v;
  return e0 / e1;
}

// batched top-16 update: 8 new distances d[0..7] vs sorted-asc bd[0..15]
__device__ __forceinline__ void topk_update(float bd[KK], float d[8]) {
  CSWAP_DESC(d[0], d[1]) CSWAP_DESC(d[2], d[3]) CSWAP_DESC(d[4], d[5]) CSWAP_DESC(d[6], d[7])
  CSWAP_DESC(d[0], d[2]) CSWAP_DESC(d[1], d[3]) CSWAP_DESC(d[4], d[6]) CSWAP_DESC(d[5], d[7])
  CSWAP_DESC(d[1], d[2]) CSWAP_DESC(d[5], d[6])
  CSWAP_DESC(d[0], d[4]) CSWAP_DESC(d[1], d[5]) CSWAP_DESC(d[2], d[6]) CSWAP_DESC(d[3], d[7])
  CSWAP_DESC(d[2], d[4]) CSWAP_DESC(d[3], d[5])
  CSWAP_DESC(d[1], d[2]) CSWAP_DESC(d[3], d[4]) CSWAP_DESC(d[5], d[6])
#pragma unroll
  for (int i = 0; i < 8; ++i) bd[8 + i] = fminf(bd[8 + i], d[i]);
#pragma unroll
  for (int i = 0; i < 8; ++i)  CSWAP_ASC(bd[i], bd[i + 8])
#pragma unroll
  for (int i = 0; i < 4; ++i)  CSWAP_ASC(bd[i], bd[i + 4])
#pragma unroll
  for (int i = 8; i < 12; ++i) CSWAP_ASC(bd[i], bd[i + 4])
#pragma unroll
  for (int g = 0; g < 4; ++g) {
    CSWAP_ASC(bd[4 * g + 0], bd[4 * g + 2]) CSWAP_ASC(bd[4 * g + 1], bd[4 * g + 3])
    CSWAP_ASC(bd[4 * g + 0], bd[4 * g + 1]) CSWAP_ASC(bd[4 * g + 2], bd[4 * g + 3])
  }
}

// ---------------- single fused kernel: tau + filter + select + eigen --------
__global__ __launch_bounds__(512, 4) void filter_select_kernel(
    const float* __restrict__ x, float* __restrict__ out) {
  extern __shared__ __align__(16) char smem[];
  float4* samp = (float4*)smem;                              // phase 0 scan
  float (*s_t)[64][17] = (float (*)[64][17])smem;            // phase 0 merge
  unsigned short* s_idx = (unsigned short*)smem;             // phase 1
  unsigned short* s_cnt = (unsigned short*)(smem + 34848);   // [8][64]
  float* s_tau = (float*)(smem + 35872);                     // [64]

  const int tid   = threadIdx.x;
  const int lane  = tid & 63;
  const int w     = __builtin_amdgcn_readfirstlane(tid >> 6);
  const int group = blockIdx.x;              // 0..511
  const int batch = group >> 7;
  const int qbase = (group & 127) * QPB;
  const float* __restrict__ Xb = x + (size_t)batch * NP * 3;

  const float qx = Xb[3 * (qbase + lane) + 0];
  const float qy = Xb[3 * (qbase + lane) + 1];
  const float qz = Xb[3 * (qbase + lane) + 2];

  // ---- phase 0: tau = 16th-smallest diff-d over sample [0,2048) ----
  {
    const float4* X4 = (const float4*)Xb;    // batch base is 16B-aligned
#pragma unroll
    for (int r = 0; r < 3; ++r)              // 1536 float4 = 2048 points
      samp[r * 512 + tid] = X4[r * 512 + tid];
  }
  __syncthreads();

  float bdA[KK], bdB[KK];
  {
    const float* sf = (const float*)samp;
#pragma unroll
    for (int t = 0; t < KK; ++t) { bdA[t] = 3.4e38f; bdB[t] = 3.4e38f; }

    const int j0 = w * TTCH;
    for (int jj = 0; jj < TTCH; jj += 16) {
      float dA[8], dB[8];
#pragma unroll
      for (int u = 0; u < 8; ++u) {
        const int j = 3 * (j0 + jj + u);     // uniform LDS addr: broadcast
        dA[u] = diff_d2(qx, qy, qz, sf[j], sf[j + 1], sf[j + 2]);
      }
#pragma unroll
      for (int u = 0; u < 8; ++u) {
        const int j = 3 * (j0 + jj + 8 + u);
        dB[u] = diff_d2(qx, qy, qz, sf[j], sf[j + 1], sf[j + 2]);
      }
      topk_update(bdA, dA);                  // two independent chains
      topk_update(bdB, dB);
    }
    topk_update(bdA, &bdB[0]);               // exact union merge
    topk_update(bdA, &bdB[8]);
  }
  __syncthreads();                           // all samp reads done

#pragma unroll
  for (int t = 0; t < KK; ++t) s_t[w][lane][t] = bdA[t];  // overlays samp
  __syncthreads();

  if (w == 0) {                              // wave-uniform merge
    float md[KK];
#pragma unroll
    for (int t = 0; t < KK; ++t) md[t] = s_t[0][lane][t];
#pragma unroll
    for (int s2 = 1; s2 < NBCH; ++s2) {
      float d[KK];
#pragma unroll
      for (int t = 0; t < KK; ++t) d[t] = s_t[s2][lane][t];
      topk_update(md, &d[0]);
      topk_update(md, &d[8]);
    }
    s_tau[lane] = md[KK - 1];
  }
  __syncthreads();                           // s_tau ready; s_t reads done

  // ---- phase 1: filter (branchless append; 12 float4 per 16 cands) ----
  {
    const int j0 = w * BCH;
    const float tau = s_tau[lane] + TAU_MARGIN;
    unsigned short* Srow = &s_idx[w * SCH + lane * SROW];
    int cnt = 0;
    for (int jj = 0; jj < BCH; jj += 16) {
      const float4* xp = (const float4*)(Xb + (size_t)(j0 + jj) * 3);
      float4 cv[12];
#pragma unroll
      for (int u = 0; u < 12; ++u) cv[u] = xp[u];  // 12 loads in flight
      const float* f = (const float*)cv;           // static idx: reg aliasing
#pragma unroll
      for (int u = 0; u < 16; ++u) {
        const float d = diff_d2(qx, qy, qz, f[3 * u], f[3 * u + 1], f[3 * u + 2]);
        const int wofs = (cnt < CAP) ? cnt : CAP;  // clamp into row pad
        Srow[1 + wofs] = (unsigned short)(j0 + jj + u);  // unconditional write
        cnt += (d <= tau) ? 1 : 0;                 // advance only on hit
      }
    }
    s_cnt[w * 64 + lane] = (unsigned short)cnt;
  }
  __syncthreads();

  // ---- phase 2: 8 threads/query; thread (q,p) -> chunk p's top-16 keys ----
  const int qlq = tid >> 3;                  // query-in-group 0..63
  const int pch = tid & 7;                   // source chunk 0..7
  unsigned long long slots[KK];
#pragma unroll
  for (int t = 0; t < KK; ++t) slots[t] = PADKEY;
  {
    const float q2x = Xb[3 * (qbase + qlq) + 0];
    const float q2y = Xb[3 * (qbase + qlq) + 1];
    const float q2z = Xb[3 * (qbase + qlq) + 2];
    const float sq2 = ref_sq(q2x, q2y, q2z);
    const unsigned short* row = &s_idx[pch * SCH + qlq * SROW + 1];
    int cnl = (int)s_cnt[pch * 64 + qlq];
    if (cnl > CAP) cnl = CAP;                // overflow query goes fs anyway
    for (int e = 0; e < cnl; e += 8) {
      unsigned long long kv[8];
#pragma unroll
      for (int u = 0; u < 8; ++u) {
        const bool ok = (e + u) < cnl;
        const int j = ok ? (int)row[e + u] : 0;
        const float cx = Xb[3 * j], cy = Xb[3 * j + 1], cz = Xb[3 * j + 2];
        const float dd = ref_d2(q2x, q2y, q2z, sq2, cx, cy, cz);  // EXACT
        kv[u] = ok ? ((((unsigned long long)ord_f32(dd)) << 16) |
                      (unsigned int)j)       // 48-bit key: (d asc, j asc)
                   : PADKEY;
      }
#pragma unroll
      for (int u = 0; u < 8; ++u) {
        const unsigned long long k = kv[u];
        if (k < slots[KK - 1]) {
#pragma unroll
          for (int t = KK - 1; t >= 1; --t) {
            unsigned long long lo =
                (slots[t] < k) ? slots[t] : k;           // min
            slots[t] = (slots[t - 1] > lo) ? slots[t - 1] : lo;  // max
          }
          slots[0] = (slots[0] < k) ? slots[0] : k;
        }
      }
    }
  }

  // ---- butterfly merge across the 8 chunk-threads (register/shuffle only) --
  // rounds m=1,2,4 within each 8-lane group; halver vs reversed partner +
  // bitonic merge-16 asc cleanup. Deterministic => all 8 lanes end with the
  // identical sorted global top-16 (same multiset as proven tournament).
#pragma unroll
  for (int m = 1; m <= 4; m <<= 1) {
    unsigned long long pr[KK];
#pragma unroll
    for (int t = 0; t < KK; ++t)
      pr[t] = (unsigned long long)__shfl_xor((long long)slots[t], m, 64);
    // halver: slots[i] = min(slots[i], partner[15-i])  (bitonic result)
#pragma unroll
    for (int t = 0; t < KK; ++t) {
      const unsigned long long b = pr[KK - 1 - t];
      slots[t] = (slots[t] < b) ? slots[t] : b;
    }
    // bitonic merge-16 ascending cleanup
#pragma unroll
    for (int i = 0; i < 8; ++i)  CSWAP_U64(slots[i], slots[i + 8])
#pragma unroll
    for (int i = 0; i < 4; ++i)  CSWAP_U64(slots[i], slots[i + 4])
#pragma unroll
    for (int i = 8; i < 12; ++i) CSWAP_U64(slots[i], slots[i + 4])
#pragma unroll
    for (int g = 0; g < 4; ++g) {
      CSWAP_U64(slots[4 * g + 0], slots[4 * g + 2])
      CSWAP_U64(slots[4 * g + 1], slots[4 * g + 3])
      CSWAP_U64(slots[4 * g + 0], slots[4 * g + 1])
      CSWAP_U64(slots[4 * g + 2], slots[4 * g + 3])
    }
  }

  // ---- phase 3: chunk-thread 0 of each query: covariance + eigen ----
  if (pch == 0) {
    const int ql = qlq;
    const int qg = batch * NP + qbase + ql;
    const float q2x = Xb[3 * (qbase + ql) + 0];
    const float q2y = Xb[3 * (qbase + ql) + 1];
    const float q2z = Xb[3 * (qbase + ql) + 2];
    const float sq2 = ref_sq(q2x, q2y, q2z);

    int total = 0;
    bool fs = false;
#pragma unroll
    for (int p = 0; p < NBCH; ++p) {
      const int c = (int)s_cnt[p * 64 + ql];
      if (c > CAP) fs = true;
      total += c;
    }
    if (total < KK) fs = true;

    int mjr[KK];
    if (!fs) {
#pragma unroll
      for (int t = 0; t < KK; ++t) mjr[t] = (int)(slots[t] & 0xFFFFull);
    } else {
      // exact full-scan insertion with index tracking (verbatim-proven)
      float md[KK];
#pragma unroll
      for (int t = 0; t < KK; ++t) { md[t] = 3.4e38f; mjr[t] = 0; }
      for (int j = 0; j < NP; ++j) {
        float d = ref_d2(q2x, q2y, q2z, sq2,
                         Xb[3 * j], Xb[3 * j + 1], Xb[3 * j + 2]);
        if (d < md[KK - 1]) {
          bool c0 = d < md[0];
#pragma unroll
          for (int t = KK - 1; t >= 1; --t) {
            bool cl = d < md[t];
            bool cp = d < md[t - 1];
            float nv = fmaxf(md[t - 1], fminf(md[t], d));
            mjr[t] = cl ? (cp ? mjr[t - 1] : j) : mjr[t];
            md[t] = nv;
          }
          mjr[0] = c0 ? j : mjr[0];
          md[0] = fminf(md[0], d);
        }
      }
    }

    // covariance in merged (d,j) order == proven chain order
    float px[KK], py[KK], pz[KK];
#pragma unroll
    for (int s = 0; s < KK; ++s) {
      px[s] = Xb[3 * mjr[s]];
      py[s] = Xb[3 * mjr[s] + 1];
      pz[s] = Xb[3 * mjr[s] + 2];
    }

    float sx = 0.f, sy = 0.f, sz = 0.f;
#pragma unroll
    for (int s = 0; s < KK; ++s) {
      sx = __fadd_rn(sx, px[s]);
      sy = __fadd_rn(sy, py[s]);
      sz = __fadd_rn(sz, pz[s]);
    }
    const float k1 = 1.0f / KK;
    const float mx = sx * k1, my = sy * k1, mz = sz * k1;

    float cxx = 0.f, cxy = 0.f, cxz = 0.f, cyy = 0.f, cyz = 0.f, czz = 0.f;
#pragma unroll
    for (int s = 0; s < KK; ++s) {
      float dx = __fsub_rn(px[s], mx);
      float dy = __fsub_rn(py[s], my);
      float dz = __fsub_rn(pz[s], mz);
      cxx = __fadd_rn(cxx, __fmul_rn(dx, dx));
      cxy = __fadd_rn(cxy, __fmul_rn(dx, dy));
      cxz = __fadd_rn(cxz, __fmul_rn(dx, dz));
      cyy = __fadd_rn(cyy, __fmul_rn(dy, dy));
      cyz = __fadd_rn(cyz, __fmul_rn(dy, dz));
      czz = __fadd_rn(czz, __fmul_rn(dz, dz));
    }

    out[qg] = (float)eigen_ratio_tail(cxx, cyy, czz, cxy, cxz, cyz, k1);
  }
}

extern "C" void kernel_launch(void* const* d_in, const int* in_sizes, int n_in,
                              void* d_out, int out_size, void* d_ws, size_t ws_size,
                              hipStream_t stream) {
  const float* x = (const float*)d_in[0];
  float* out = (float*)d_out;
  const size_t fs_lds = 36128;   // samp/s_t/s_idx union + s_cnt + s_tau
  filter_select_kernel<<<dim3(512), dim3(512), fs_lds, stream>>>(x, out);
}

// Round 20
// 183.381 us; speedup vs baseline: 1.1033x; 1.1033x over previous
//
#include <hip/hip_runtime.h>
#include <math.h>

#define NB 4
#define NP 8192
#define KK 16
#define QPB 64
#define NPTS (NB * NP)

// ---- geometry (round 20: R18 + register butterfly merge; append reverted) --
#define TSAMP 2048            // tau sample = candidates [0,2048)
#define TTCH 256              // tau subchunk per wave (2048/8)
#define BCH 1024              // filter chunk size
#define NBCH 8                // 8 chunks cover [0,8192)
#define CAP 30                // per-(query,chunk) capacity (R13-proven geometry)
#define SROW 34               // u16 per (chunk,query) LDS row (odd dwords)
#define SCH (64 * SROW + 2)   // LDS chunk stride in u16 (=2178)
#define PADKEY 0xFFFFFFFFFFFFull   // 48-bit all-ones
#define TAU_MARGIN 2.5e-4f    // >= 2x the |diff_d - ref_d| bound (~3.5e-5)
// Dynamic LDS (36,128 B):
//   [0,34848)   union{ samp float4[1536] -> s_t f32[8][64][17] -> s_idx
//               u16 8x2178 } (barrier-separated phases)
//   [34848,35872) s_cnt u16[8][64];  [35872,36128) s_tau f32[64].
//
// Correctness chain (fail-safe, independent of tau's value):
//  S = {j: diff_d(j) <= tau + MARGIN}, tau = 16th-smallest diff_d over the
//  2048-sample; |diff_d - ref_d| <= ~3.5e-5 << MARGIN => exact ref top-16
//  inside S whenever |S| >= 16. Phase 2 re-ranks S with EXACT ref-rounded
//  distance; 48-bit key (ord(d)<<16)|j = total order (d asc, j asc).
//  Per-chunk top-16-by-key; 3-round XOR-butterfly (halver vs reversed
//  partner + bitonic merge-16 cleanup) is a deterministic merge network =>
//  all 8 lanes end with the identical sorted global top-16 == the proven
//  tournament output (absmax 0.0, R12-R18). Chunk cnt > CAP or total < 16
//  => in-kernel exact full-scan.
//  R19 lesson: branchless (unconditional) LDS append multiplied write
//  traffic 16x -> 15.5M bank conflicts, +21us. Conditional append restored.

// comparator macros (exact: min/max introduce no rounding)
#define CSWAP_DESC(a, b) { float _lo = fminf(a, b); float _hi = fmaxf(a, b); a = _hi; b = _lo; }
#define CSWAP_ASC(a, b)  { float _lo = fminf(a, b); float _hi = fmaxf(a, b); a = _lo; b = _hi; }
#define CSWAP_U64(a, b)  { unsigned long long _lo = (a < b) ? a : b; \
                           unsigned long long _hi = (a < b) ? b : a; a = _lo; b = _hi; }

__device__ __forceinline__ float ref_sq(float x, float y, float z) {
  return __fadd_rn(__fadd_rn(__fmul_rn(x, x), __fmul_rn(y, y)), __fmul_rn(z, z));
}

// reference-rounded d2 = (sqq + sqc) - 2*dot (the exact selection metric)
__device__ __forceinline__ float ref_d2(float qx, float qy, float qz, float sqq,
                                        float cx, float cy, float cz) {
  float sqc = ref_sq(cx, cy, cz);
  float dot = __fadd_rn(__fadd_rn(__fmul_rn(qx, cx), __fmul_rn(qy, cy)),
                        __fmul_rn(qz, cz));
  float s = __fadd_rn(sqq, sqc);
  return __fmaf_rn(-2.0f, dot, s);
}

// diff-form distance (6 VALU, near-exact): used for tau + filter only
__device__ __forceinline__ float diff_d2(float qx, float qy, float qz,
                                         float cx, float cy, float cz) {
  float dx = cx - qx, dy = cy - qy, dz = cz - qz;
  return __fmaf_rn(dz, dz, __fmaf_rn(dy, dy, dx * dx));
}

// order-preserving float->u32 (total order == float compare for non-NaN)
__device__ __forceinline__ unsigned int ord_f32(float d) {
  unsigned int b = __float_as_uint(d);
  return b ^ ((b >> 31) ? 0xFFFFFFFFu : 0x80000000u);
}

// ---- eigen-ratio tail (R11-R18-proven: absmax 0.0 measured) ----
__device__ __forceinline__ double eigen_ratio_tail(
    float cxx, float cyy, float czz, float cxy, float cxz, float cyz,
    float k1) {
  double a   = (double)__fmul_rn(cxx, k1), b = (double)__fmul_rn(cyy, k1);
  double c2  = (double)__fmul_rn(czz, k1);
  double dxy = (double)__fmul_rn(cxy, k1), exz = (double)__fmul_rn(cxz, k1);
  double fyz = (double)__fmul_rn(cyz, k1);
  double qm = (a + b + c2) / 3.0;
  double p1 = dxy * dxy + exz * exz + fyz * fyz;
  double aa = a - qm, bb = b - qm, cc = c2 - qm;
  double p2 = aa * aa + bb * bb + cc * cc + 2.0 * p1;
  if (p2 <= 0.0) return 1.0;
  double p  = sqrt(p2 / 6.0);
  double ip = 1.0 / p;
  double b00 = aa * ip, b11 = bb * ip, b22 = cc * ip;
  double b01 = dxy * ip, b02 = exz * ip, b12 = fyz * ip;
  double detB = b00 * (b11 * b22 - b12 * b12)
              - b01 * (b01 * b22 - b12 * b02)
              + b02 * (b01 * b12 - b11 * b02);
  double r = 0.5 * detB;
  r = fmin(1.0, fmax(-1.0, r));
  const double dcl = 2.0 * r;
  float phif = acosf((float)r) * (1.0f / 3.0f);
  double y0 = 2.0 * (double)cosf(phif);
  double y2 = 2.0 * (double)cosf(phif + 2.0943951f);
#pragma unroll
  for (int it = 0; it < 3; ++it) {
    double g0 = 3.0 * (y0 * y0 - 1.0);
    if (fabs(g0) > 1e-4) y0 -= (y0 * y0 * y0 - 3.0 * y0 - dcl) / g0;
    double g2 = 3.0 * (y2 * y2 - 1.0);
    if (fabs(g2) > 1e-4) y2 -= (y2 * y2 * y2 - 3.0 * y2 - dcl) / g2;
  }
  double e0 = qm + p * y0;
  double e2v = qm + p * y2;
  double e1 = 3.0 * qm - e0 - e2v;
  return e0 / e1;
}

// batched top-16 update: 8 new distances d[0..7] vs sorted-asc bd[0..15]
__device__ __forceinline__ void topk_update(float bd[KK], float d[8]) {
  CSWAP_DESC(d[0], d[1]) CSWAP_DESC(d[2], d[3]) CSWAP_DESC(d[4], d[5]) CSWAP_DESC(d[6], d[7])
  CSWAP_DESC(d[0], d[2]) CSWAP_DESC(d[1], d[3]) CSWAP_DESC(d[4], d[6]) CSWAP_DESC(d[5], d[7])
  CSWAP_DESC(d[1], d[2]) CSWAP_DESC(d[5], d[6])
  CSWAP_DESC(d[0], d[4]) CSWAP_DESC(d[1], d[5]) CSWAP_DESC(d[2], d[6]) CSWAP_DESC(d[3], d[7])
  CSWAP_DESC(d[2], d[4]) CSWAP_DESC(d[3], d[5])
  CSWAP_DESC(d[1], d[2]) CSWAP_DESC(d[3], d[4]) CSWAP_DESC(d[5], d[6])
#pragma unroll
  for (int i = 0; i < 8; ++i) bd[8 + i] = fminf(bd[8 + i], d[i]);
#pragma unroll
  for (int i = 0; i < 8; ++i)  CSWAP_ASC(bd[i], bd[i + 8])
#pragma unroll
  for (int i = 0; i < 4; ++i)  CSWAP_ASC(bd[i], bd[i + 4])
#pragma unroll
  for (int i = 8; i < 12; ++i) CSWAP_ASC(bd[i], bd[i + 4])
#pragma unroll
  for (int g = 0; g < 4; ++g) {
    CSWAP_ASC(bd[4 * g + 0], bd[4 * g + 2]) CSWAP_ASC(bd[4 * g + 1], bd[4 * g + 3])
    CSWAP_ASC(bd[4 * g + 0], bd[4 * g + 1]) CSWAP_ASC(bd[4 * g + 2], bd[4 * g + 3])
  }
}

// ---------------- single fused kernel: tau + filter + select + eigen --------
__global__ __launch_bounds__(512, 4) void filter_select_kernel(
    const float* __restrict__ x, float* __restrict__ out) {
  extern __shared__ __align__(16) char smem[];
  float4* samp = (float4*)smem;                              // phase 0 scan
  float (*s_t)[64][17] = (float (*)[64][17])smem;            // phase 0 merge
  unsigned short* s_idx = (unsigned short*)smem;             // phase 1
  unsigned short* s_cnt = (unsigned short*)(smem + 34848);   // [8][64]
  float* s_tau = (float*)(smem + 35872);                     // [64]

  const int tid   = threadIdx.x;
  const int lane  = tid & 63;
  const int w     = __builtin_amdgcn_readfirstlane(tid >> 6);
  const int group = blockIdx.x;              // 0..511
  const int batch = group >> 7;
  const int qbase = (group & 127) * QPB;
  const float* __restrict__ Xb = x + (size_t)batch * NP * 3;

  const float qx = Xb[3 * (qbase + lane) + 0];
  const float qy = Xb[3 * (qbase + lane) + 1];
  const float qz = Xb[3 * (qbase + lane) + 2];

  // ---- phase 0: tau = 16th-smallest diff-d over sample [0,2048) ----
  {
    const float4* X4 = (const float4*)Xb;    // batch base is 16B-aligned
#pragma unroll
    for (int r = 0; r < 3; ++r)              // 1536 float4 = 2048 points
      samp[r * 512 + tid] = X4[r * 512 + tid];
  }
  __syncthreads();

  float bdA[KK], bdB[KK];
  {
    const float* sf = (const float*)samp;
#pragma unroll
    for (int t = 0; t < KK; ++t) { bdA[t] = 3.4e38f; bdB[t] = 3.4e38f; }

    const int j0 = w * TTCH;
    for (int jj = 0; jj < TTCH; jj += 16) {
      float dA[8], dB[8];
#pragma unroll
      for (int u = 0; u < 8; ++u) {
        const int j = 3 * (j0 + jj + u);     // uniform LDS addr: broadcast
        dA[u] = diff_d2(qx, qy, qz, sf[j], sf[j + 1], sf[j + 2]);
      }
#pragma unroll
      for (int u = 0; u < 8; ++u) {
        const int j = 3 * (j0 + jj + 8 + u);
        dB[u] = diff_d2(qx, qy, qz, sf[j], sf[j + 1], sf[j + 2]);
      }
      topk_update(bdA, dA);                  // two independent chains
      topk_update(bdB, dB);
    }
    topk_update(bdA, &bdB[0]);               // exact union merge
    topk_update(bdA, &bdB[8]);
  }
  __syncthreads();                           // all samp reads done

#pragma unroll
  for (int t = 0; t < KK; ++t) s_t[w][lane][t] = bdA[t];  // overlays samp
  __syncthreads();

  if (w == 0) {                              // wave-uniform merge
    float md[KK];
#pragma unroll
    for (int t = 0; t < KK; ++t) md[t] = s_t[0][lane][t];
#pragma unroll
    for (int s2 = 1; s2 < NBCH; ++s2) {
      float d[KK];
#pragma unroll
      for (int t = 0; t < KK; ++t) d[t] = s_t[s2][lane][t];
      topk_update(md, &d[0]);
      topk_update(md, &d[8]);
    }
    s_tau[lane] = md[KK - 1];
  }
  __syncthreads();                           // s_tau ready; s_t reads done

  // ---- phase 1: filter (conditional append, R18-proven; 12 float4/16) ----
  {
    const int j0 = w * BCH;
    const float tau = s_tau[lane] + TAU_MARGIN;
    unsigned short* Srow = &s_idx[w * SCH + lane * SROW];
    int cnt = 0;
    for (int jj = 0; jj < BCH; jj += 16) {
      const float4* xp = (const float4*)(Xb + (size_t)(j0 + jj) * 3);
      float4 cv[12];
#pragma unroll
      for (int u = 0; u < 12; ++u) cv[u] = xp[u];  // 12 loads in flight
      const float* f = (const float*)cv;           // static idx: reg aliasing
#pragma unroll
      for (int u = 0; u < 16; ++u) {
        float d = diff_d2(qx, qy, qz, f[3 * u], f[3 * u + 1], f[3 * u + 2]);
        if (d <= tau) {
          if (cnt < CAP) Srow[1 + cnt] = (unsigned short)(j0 + jj + u);
          ++cnt;                             // count ALL survivors
        }
      }
    }
    s_cnt[w * 64 + lane] = (unsigned short)cnt;
  }
  __syncthreads();

  // ---- phase 2: 8 threads/query; thread (q,p) -> chunk p's top-16 keys ----
  const int qlq = tid >> 3;                  // query-in-group 0..63
  const int pch = tid & 7;                   // source chunk 0..7
  unsigned long long slots[KK];
#pragma unroll
  for (int t = 0; t < KK; ++t) slots[t] = PADKEY;
  {
    const float q2x = Xb[3 * (qbase + qlq) + 0];
    const float q2y = Xb[3 * (qbase + qlq) + 1];
    const float q2z = Xb[3 * (qbase + qlq) + 2];
    const float sq2 = ref_sq(q2x, q2y, q2z);
    const unsigned short* row = &s_idx[pch * SCH + qlq * SROW + 1];
    int cnl = (int)s_cnt[pch * 64 + qlq];
    if (cnl > CAP) cnl = CAP;                // overflow query goes fs anyway
    for (int e = 0; e < cnl; e += 8) {
      unsigned long long kv[8];
#pragma unroll
      for (int u = 0; u < 8; ++u) {
        const bool ok = (e + u) < cnl;
        const int j = ok ? (int)row[e + u] : 0;
        const float cx = Xb[3 * j], cy = Xb[3 * j + 1], cz = Xb[3 * j + 2];
        const float dd = ref_d2(q2x, q2y, q2z, sq2, cx, cy, cz);  // EXACT
        kv[u] = ok ? ((((unsigned long long)ord_f32(dd)) << 16) |
                      (unsigned int)j)       // 48-bit key: (d asc, j asc)
                   : PADKEY;
      }
#pragma unroll
      for (int u = 0; u < 8; ++u) {
        const unsigned long long k = kv[u];
        if (k < slots[KK - 1]) {
#pragma unroll
          for (int t = KK - 1; t >= 1; --t) {
            unsigned long long lo =
                (slots[t] < k) ? slots[t] : k;           // min
            slots[t] = (slots[t - 1] > lo) ? slots[t - 1] : lo;  // max
          }
          slots[0] = (slots[0] < k) ? slots[0] : k;
        }
      }
    }
  }

  // ---- butterfly merge across the 8 chunk-threads (register/shuffle only) --
  // rounds m=1,2,4; halver vs reversed partner + bitonic merge-16 cleanup.
  // Deterministic network => all 8 lanes end with the identical sorted
  // global top-16 (same multiset as the proven tournament merge).
#pragma unroll
  for (int m = 1; m <= 4; m <<= 1) {
    unsigned long long pr[KK];
#pragma unroll
    for (int t = 0; t < KK; ++t)
      pr[t] = (unsigned long long)__shfl_xor((long long)slots[t], m, 64);
#pragma unroll
    for (int t = 0; t < KK; ++t) {
      const unsigned long long b = pr[KK - 1 - t];
      slots[t] = (slots[t] < b) ? slots[t] : b;     // halver keeps 16 smallest
    }
#pragma unroll
    for (int i = 0; i < 8; ++i)  CSWAP_U64(slots[i], slots[i + 8])
#pragma unroll
    for (int i = 0; i < 4; ++i)  CSWAP_U64(slots[i], slots[i + 4])
#pragma unroll
    for (int i = 8; i < 12; ++i) CSWAP_U64(slots[i], slots[i + 4])
#pragma unroll
    for (int g = 0; g < 4; ++g) {
      CSWAP_U64(slots[4 * g + 0], slots[4 * g + 2])
      CSWAP_U64(slots[4 * g + 1], slots[4 * g + 3])
      CSWAP_U64(slots[4 * g + 0], slots[4 * g + 1])
      CSWAP_U64(slots[4 * g + 2], slots[4 * g + 3])
    }
  }

  // ---- phase 3: chunk-thread 0 of each query: covariance + eigen ----
  if (pch == 0) {
    const int ql = qlq;
    const int qg = batch * NP + qbase + ql;
    const float q2x = Xb[3 * (qbase + ql) + 0];
    const float q2y = Xb[3 * (qbase + ql) + 1];
    const float q2z = Xb[3 * (qbase + ql) + 2];
    const float sq2 = ref_sq(q2x, q2y, q2z);

    int total = 0;
    bool fs = false;
#pragma unroll
    for (int p = 0; p < NBCH; ++p) {
      const int c = (int)s_cnt[p * 64 + ql];
      if (c > CAP) fs = true;
      total += c;
    }
    if (total < KK) fs = true;

    int mjr[KK];
    if (!fs) {
#pragma unroll
      for (int t = 0; t < KK; ++t) mjr[t] = (int)(slots[t] & 0xFFFFull);
    } else {
      // exact full-scan insertion with index tracking (verbatim-proven)
      float md[KK];
#pragma unroll
      for (int t = 0; t < KK; ++t) { md[t] = 3.4e38f; mjr[t] = 0; }
      for (int j = 0; j < NP; ++j) {
        float d = ref_d2(q2x, q2y, q2z, sq2,
                         Xb[3 * j], Xb[3 * j + 1], Xb[3 * j + 2]);
        if (d < md[KK - 1]) {
          bool c0 = d < md[0];
#pragma unroll
          for (int t = KK - 1; t >= 1; --t) {
            bool cl = d < md[t];
            bool cp = d < md[t - 1];
            float nv = fmaxf(md[t - 1], fminf(md[t], d));
            mjr[t] = cl ? (cp ? mjr[t - 1] : j) : mjr[t];
            md[t] = nv;
          }
          mjr[0] = c0 ? j : mjr[0];
          md[0] = fminf(md[0], d);
        }
      }
    }

    // covariance in merged (d,j) order == proven chain order
    float px[KK], py[KK], pz[KK];
#pragma unroll
    for (int s = 0; s < KK; ++s) {
      px[s] = Xb[3 * mjr[s]];
      py[s] = Xb[3 * mjr[s] + 1];
      pz[s] = Xb[3 * mjr[s] + 2];
    }

    float sx = 0.f, sy = 0.f, sz = 0.f;
#pragma unroll
    for (int s = 0; s < KK; ++s) {
      sx = __fadd_rn(sx, px[s]);
      sy = __fadd_rn(sy, py[s]);
      sz = __fadd_rn(sz, pz[s]);
    }
    const float k1 = 1.0f / KK;
    const float mx = sx * k1, my = sy * k1, mz = sz * k1;

    float cxx = 0.f, cxy = 0.f, cxz = 0.f, cyy = 0.f, cyz = 0.f, czz = 0.f;
#pragma unroll
    for (int s = 0; s < KK; ++s) {
      float dx = __fsub_rn(px[s], mx);
      float dy = __fsub_rn(py[s], my);
      float dz = __fsub_rn(pz[s], mz);
      cxx = __fadd_rn(cxx, __fmul_rn(dx, dx));
      cxy = __fadd_rn(cxy, __fmul_rn(dx, dy));
      cxz = __fadd_rn(cxz, __fmul_rn(dx, dz));
      cyy = __fadd_rn(cyy, __fmul_rn(dy, dy));
      cyz = __fadd_rn(cyz, __fmul_rn(dy, dz));
      czz = __fadd_rn(czz, __fmul_rn(dz, dz));
    }

    out[qg] = (float)eigen_ratio_tail(cxx, cyy, czz, cxy, cxz, cyz, k1);
  }
}

extern "C" void kernel_launch(void* const* d_in, const int* in_sizes, int n_in,
                              void* d_out, int out_size, void* d_ws, size_t ws_size,
                              hipStream_t stream) {
  const float* x = (const float*)d_in[0];
  float* out = (float*)d_out;
  const size_t fs_lds = 36128;   // samp/s_t/s_idx union + s_cnt + s_tau
  filter_select_kernel<<<dim3(512), dim3(512), fs_lds, stream>>>(x, out);
}